// Round 11
// baseline (540.054 us; speedup 1.0000x reference)
//
#include <hip/hip_runtime.h>
#include <hip/hip_bf16.h>
#include <math.h>

// Problem constants (PoseMixtureVAE)
#define N_BATCH 4096
#define FRAME   267
#define LATENT  32
#define HIDDEN  256
#define GATE_H  64
#define EXPERTS 6
#define NBLK    512    // persistent grid: lb(256,2) -> 2 blocks/CU guaranteed (R8-verified)

typedef __hip_bfloat16 bf16;
typedef __bf16  bf16x8 __attribute__((ext_vector_type(8)));
typedef float   f32x4  __attribute__((ext_vector_type(4)));

__device__ __forceinline__ float eluf(float v) { return (v > 0.f) ? v : (expf(v) - 1.f); }

// ---------------------------------------------------------------------------
// Two-level grid barrier, monotonic phase, line-padded state (R8 fix):
//   bar[0]        : gen (polled line, read-only except 1 release store/phase)
//   bar[32+g*32]  : group counter g=0..7 (64 arrivals each, own 128B line)
//   bar[32+8*32]  : global counter (8 arrivals, own line)
// State memset to 0 per call; phases 1..6 monotonic (no resets -> no races).
// ---------------------------------------------------------------------------
__device__ __forceinline__ void gbar(unsigned* bar, int phase, int bid) {
    __syncthreads();
    if (threadIdx.x == 0) {
        __threadfence();   // block's stores -> visible device-wide (R8-verified)
        unsigned* ggen = bar;
        unsigned* grp  = bar + 32 + (bid & 7) * 32;
        unsigned* gcnt = bar + 32 + 8 * 32;
        const unsigned ph = (unsigned)phase;
        unsigned old = __hip_atomic_fetch_add(grp, 1u, __ATOMIC_ACQ_REL, __HIP_MEMORY_SCOPE_AGENT);
        if (old == 64u * ph - 1u) {
            unsigned o2 = __hip_atomic_fetch_add(gcnt, 1u, __ATOMIC_ACQ_REL, __HIP_MEMORY_SCOPE_AGENT);
            if (o2 == 8u * ph - 1u)
                __hip_atomic_store(ggen, ph, __ATOMIC_RELEASE, __HIP_MEMORY_SCOPE_AGENT);
        }
        while (__hip_atomic_load(ggen, __ATOMIC_ACQUIRE, __HIP_MEMORY_SCOPE_AGENT) < ph)
            __builtin_amdgcn_s_sleep(2);
        __threadfence();   // invalidate stale caches before next stage's reads
    }
    __syncthreads();
}

struct WEnt { const float* src; bf16* dst; int K, M, Mtot, mOff, Ksteps, Mtiles, cum; };
struct WTab { WEnt e[10]; int total; };

struct Args {
    const float *x, *c, *eps;
    const float *enc_b1, *enc_b2, *g_b0, *g_b1, *g_b2, *b0, *b1, *b2;
    const float *enc_bmu, *enc_blv;
    float *out_layer, *out_mu, *out_lv;
    unsigned *bar;
    float *co, *biasCat;
    bf16 *Axc, *Axh1, *Axh2, *Azc, *Azd1, *Azd2;
    bf16 *Wt_e1, *Wt_e2, *Wt_ml, *Wt_g0, *Wt_g1, *Wt_g2, *Wt_w0, *Wt_w1, *Wt_w2;
};

// ---------------------------------------------------------------------------
// Persistent GEMM stage (R10's 16-row/RF=1 wave structure):
//   block bid -> row-block bid>>1 (16 rows), col-half bid&1 of TCOL 64-col tiles.
//   A (16 x Kpad) staged once in LDS; B streamed to regs (1KB/wave coalesced
//   from k-block repack [E][KSTEPS][Mtot][32]).
// Caller must gbar() before sA reuse.
// ---------------------------------------------------------------------------
template<int KSTEPS, int E>
__device__ void gemm_stage16(
    const bf16* __restrict__ A, const bf16* __restrict__ Wt,
    const float* __restrict__ bias, const float* __restrict__ coeff,
    int M, int Mtot, int TCOL,
    float* __restrict__ Cf, int ldc, bf16* __restrict__ Cb, int ldcb, int act,
    int bid, int tid, bf16* sA, float* sCo)
{
    constexpr int Kpad = KSTEPS * 32;
    constexpr int strideA = Kpad + 8;
    const int w = tid >> 6, lane = tid & 63, ml = lane & 15, quad = lane >> 4;
    const int row0 = (bid >> 1) * 16;
    const int ch = bid & 1;
    const int nh = (TCOL + 1) >> 1;
    const int gA = ch * nh;
    const int gB = (gA + nh < TCOL) ? gA + nh : TCOL;

    if (tid < 16 * E) {
        const int e = tid >> 4, r = tid & 15;
        sCo[tid] = coeff ? coeff[(size_t)(row0 + r) * EXPERTS + e] : 1.f;
    }
    {   // stage A: 16 rows x Kpad
        const int r = tid >> 4, kt = (tid & 15) * 8;
        for (int kk = kt; kk < Kpad; kk += 128)
            *(float4*)(sA + r * strideA + kk) =
                *(const float4*)(A + (size_t)(row0 + r) * Kpad + kk);
    }
    __syncthreads();

    for (int g = gA; g < gB; ++g) {
        const int col = g * 64 + 16 * w + ml;
        f32x4 acc = (f32x4){0.f, 0.f, 0.f, 0.f};
        for (int e = 0; e < E; ++e) {
            f32x4 p = (f32x4){0.f, 0.f, 0.f, 0.f};
            const bf16* wp = Wt + ((size_t)e * KSTEPS * Mtot + col) * 32 + quad * 8;
            #pragma unroll
            for (int ks = 0; ks < KSTEPS; ++ks) {
                const bf16x8 b  = *(const bf16x8*)(wp + (size_t)ks * Mtot * 32);
                const bf16x8 av = *(const bf16x8*)(sA + ml * strideA + ks * 32 + quad * 8);
                p = __builtin_amdgcn_mfma_f32_16x16x32_bf16(av, b, p, 0, 0, 0);
            }
            const float bv = (col < M) ? bias[(size_t)e * M + col] : 0.f;
            #pragma unroll
            for (int rg = 0; rg < 4; ++rg)
                acc[rg] += sCo[e * 16 + quad * 4 + rg] * (p[rg] + bv);
        }
        if (col < M) {
            #pragma unroll
            for (int rg = 0; rg < 4; ++rg) {
                const int gr = row0 + quad * 4 + rg;
                float v = acc[rg];
                if (act) v = eluf(v);
                if (Cf) Cf[(size_t)gr * ldc + col] = v;
                if (Cb) Cb[(size_t)gr * ldcb + col] = __float2bfloat16(v);
            }
        }
    }
}

// ---------------------------------------------------------------------------
__global__ __launch_bounds__(256, 2) void fused(Args a, WTab tab) {
    __shared__ bf16  sA[16 * 552];           // 17664B (Kpad<=544, stride 552)
    __shared__ char  r1[8448];               // mid scratch / repack tbuf
    __shared__ float sCo[16 * EXPERTS];      // 384B
    const int tid = threadIdx.x;
    const int bid = blockIdx.x;
    const int w = tid >> 6, lane = tid & 63, ml = lane & 15, quad = lane >> 4;

    // ================= S0: input conversion + weight repack =================
    if (bid == 0 && tid < 64)
        a.biasCat[tid] = (tid < 32) ? a.enc_bmu[tid] : a.enc_blv[tid - 32];
    #pragma unroll 1
    for (int i = 0; i < 8; ++i) {
        const int r = bid * 8 + i;
        for (int col = tid; col < 544; col += 256) {
            const size_t o = (size_t)r * 544 + col;
            float vx = 0.f;
            if (col < FRAME)          vx = a.x[(size_t)r * FRAME + col];
            else if (col < 2 * FRAME) vx = a.c[(size_t)r * FRAME + col - FRAME];
            a.Axc[o] = __float2bfloat16(vx);
            if (col < FRAME) {
                const bf16 v = __float2bfloat16(a.x[(size_t)r * FRAME + col]);
                a.Axh1[o] = v; a.Axh2[o] = v;
            } else if (col >= FRAME + HIDDEN) {
                const bf16 zv = __float2bfloat16(0.f);
                a.Axh1[o] = zv; a.Axh2[o] = zv;
            }
            if (col >= 32 && col < 320) {
                const float vc = (col < 32 + FRAME) ? a.c[(size_t)r * FRAME + col - 32] : 0.f;
                a.Azc[(size_t)r * 320 + col] = __float2bfloat16(vc);
            }
        }
    }
    {   // weight repack units strided over blocks (block-uniform loop count OK)
        float (*tbuf)[33] = (float(*)[33])r1;   // 32x33 f32 = 4224B
        const int tx = tid & 31, ty = tid >> 5;
        #pragma unroll 1
        for (int u = bid; u < tab.total; u += NBLK) {
            int i = 0;
            while (i < 9 && u >= tab.e[i + 1].cum) ++i;
            const WEnt en = tab.e[i];
            const int t = u - en.cum;
            const int perE = en.Ksteps * en.Mtiles;
            const int e = t / perE;
            const int rr = t - e * perE;
            const int mt = rr / en.Ksteps;
            const int ks = rr - mt * en.Ksteps;
            const float* src = en.src + (size_t)e * en.K * en.M;
            __syncthreads();
            #pragma unroll
            for (int i0 = 0; i0 < 32; i0 += 8) {
                const int k = ks * 32 + i0 + ty, m = mt * 32 + tx;
                tbuf[i0 + ty][tx] = (k < en.K && m < en.M) ? src[(size_t)k * en.M + m] : 0.f;
            }
            __syncthreads();
            bf16* dst = en.dst + ((size_t)(e * en.Ksteps + ks) * en.Mtot + en.mOff + mt * 32) * 32;
            #pragma unroll
            for (int i0 = 0; i0 < 32; i0 += 8)
                dst[(size_t)(i0 + ty) * 32 + tx] = __float2bfloat16(tbuf[tx][i0 + ty]);
        }
    }
    gbar(a.bar, 1, bid);

    // ================= S1: h1 = elu([x|c]@W+b) -> Axh1[:,267:523] ===========
    gemm_stage16<17, 1>(a.Axc, a.Wt_e1, a.enc_b1, nullptr, 256, 256, 4,
                        nullptr, 0, a.Axh1 + FRAME, 544, 1, bid, tid, sA, sCo);
    gbar(a.bar, 2, bid);

    // ================= S2: h2 = elu([x|h1]@W+b) -> Axh2[:,267:523] ==========
    gemm_stage16<17, 1>(a.Axh1, a.Wt_e2, a.enc_b2, nullptr, 256, 256, 4,
                        nullptr, 0, a.Axh2 + FRAME, 544, 1, bid, tid, sA, sCo);
    gbar(a.bar, 3, bid);

    // ====== S3: mu|lv GEMM + z + gate chain + softmax (blocks 0..255) =======
    if (bid < 256) {
        const int row0 = bid * 16;
        float* sML = (float*)r1;                       // 16x64 f32 = 4KB
        {   // stage Axh2 rows (Kpad 544, stride 552)
            const int r = tid >> 4, kt = (tid & 15) * 8;
            for (int kk = kt; kk < 544; kk += 128)
                *(float4*)(sA + r * 552 + kk) =
                    *(const float4*)(a.Axh2 + (size_t)(row0 + r) * 544 + kk);
        }
        __syncthreads();
        {   // mu|lv: M=64, wave w -> cols 16w..16w+15
            const int col = 16 * w + ml;
            f32x4 p = (f32x4){0.f, 0.f, 0.f, 0.f};
            const bf16* wp = a.Wt_ml + (size_t)col * 32 + quad * 8;
            #pragma unroll
            for (int ks = 0; ks < 17; ++ks) {
                const bf16x8 b  = *(const bf16x8*)(wp + (size_t)ks * 64 * 32);
                const bf16x8 av = *(const bf16x8*)(sA + ml * 552 + ks * 32 + quad * 8);
                p = __builtin_amdgcn_mfma_f32_16x16x32_bf16(av, b, p, 0, 0, 0);
            }
            const float bv = a.biasCat[col];
            #pragma unroll
            for (int rg = 0; rg < 4; ++rg)
                sML[(quad * 4 + rg) * 64 + col] = p[rg] + bv;
        }
        __syncthreads();
        for (int i = tid; i < 16 * LATENT; i += 256) {
            const int r = i >> 5, l = i & 31;
            const float m  = sML[r * 64 + l];
            const float lv = sML[r * 64 + 32 + l];
            const int gi = (row0 + r) * LATENT + l;
            a.out_mu[gi] = m; a.out_lv[gi] = lv;
            const bf16 zb = __float2bfloat16(m + a.eps[gi] * expf(0.5f * lv));
            a.Azc [(size_t)(row0 + r) * 320 + l] = zb;
            a.Azd1[(size_t)(row0 + r) * 288 + l] = zb;
            a.Azd2[(size_t)(row0 + r) * 288 + l] = zb;
        }
        __syncthreads();
        {   // re-stage gate A = Azc rows [z|c] (Kpad 320, stride 328)
            const int r = tid >> 4, kt = (tid & 15) * 8;
            for (int kk = kt; kk < 320; kk += 128)
                *(float4*)(sA + r * 328 + kk) =
                    *(const float4*)(a.Azc + (size_t)(row0 + r) * 320 + kk);
        }
        bf16*  sG1 = (bf16*)r1;                        // 16x72 bf16 = 2304B
        bf16*  sG2 = (bf16*)(r1 + 2304);
        float* sLg = (float*)(r1 + 4608);              // 16x16 f32 = 1024B
        __syncthreads();
        {   // g1: K=320(10), M=64
            const int col = 16 * w + ml;
            f32x4 p = (f32x4){0.f, 0.f, 0.f, 0.f};
            const bf16* wp = a.Wt_g0 + (size_t)col * 32 + quad * 8;
            #pragma unroll
            for (int ks = 0; ks < 10; ++ks) {
                const bf16x8 b  = *(const bf16x8*)(wp + (size_t)ks * 64 * 32);
                const bf16x8 av = *(const bf16x8*)(sA + ml * 328 + ks * 32 + quad * 8);
                p = __builtin_amdgcn_mfma_f32_16x16x32_bf16(av, b, p, 0, 0, 0);
            }
            const float bv = a.g_b0[col];
            #pragma unroll
            for (int rg = 0; rg < 4; ++rg)
                sG1[(quad * 4 + rg) * 72 + col] = __float2bfloat16(eluf(p[rg] + bv));
        }
        __syncthreads();
        {   // g2: K=64(2), M=64
            const int col = 16 * w + ml;
            f32x4 p = (f32x4){0.f, 0.f, 0.f, 0.f};
            const bf16* wp = a.Wt_g1 + (size_t)col * 32 + quad * 8;
            #pragma unroll
            for (int ks = 0; ks < 2; ++ks) {
                const bf16x8 b  = *(const bf16x8*)(wp + (size_t)ks * 64 * 32);
                const bf16x8 av = *(const bf16x8*)(sG1 + ml * 72 + ks * 32 + quad * 8);
                p = __builtin_amdgcn_mfma_f32_16x16x32_bf16(av, b, p, 0, 0, 0);
            }
            const float bv = a.g_b1[col];
            #pragma unroll
            for (int rg = 0; rg < 4; ++rg)
                sG2[(quad * 4 + rg) * 72 + col] = __float2bfloat16(eluf(p[rg] + bv));
        }
        __syncthreads();
        if (w == 0) {   // logits: K=64(2), M=6 (Mtot 32)
            f32x4 p = (f32x4){0.f, 0.f, 0.f, 0.f};
            const bf16* wp = a.Wt_g2 + (size_t)ml * 32 + quad * 8;
            #pragma unroll
            for (int ks = 0; ks < 2; ++ks) {
                const bf16x8 b  = *(const bf16x8*)(wp + (size_t)ks * 32 * 32);
                const bf16x8 av = *(const bf16x8*)(sG2 + ml * 72 + ks * 32 + quad * 8);
                p = __builtin_amdgcn_mfma_f32_16x16x32_bf16(av, b, p, 0, 0, 0);
            }
            const float bv = (ml < EXPERTS) ? a.g_b2[ml] : 0.f;
            #pragma unroll
            for (int rg = 0; rg < 4; ++rg)
                sLg[(quad * 4 + rg) * 16 + ml] = p[rg] + bv;
        }
        __syncthreads();
        if (tid < 16) {
            float v[EXPERTS];
            float m = -1e30f;
            #pragma unroll
            for (int i = 0; i < EXPERTS; ++i) { v[i] = sLg[tid * 16 + i]; m = fmaxf(m, v[i]); }
            float s = 0.f;
            #pragma unroll
            for (int i = 0; i < EXPERTS; ++i) { v[i] = expf(v[i] - m); s += v[i]; }
            const float inv = 1.f / s;
            #pragma unroll
            for (int i = 0; i < EXPERTS; ++i)
                a.co[(size_t)(row0 + tid) * EXPERTS + i] = v[i] * inv;
        }
    }
    gbar(a.bar, 4, bid);

    // ================= S4: dh1 -> Azd1[:,32:288] ============================
    gemm_stage16<10, EXPERTS>(a.Azc, a.Wt_w0, a.b0, a.co, 256, 256, 4,
                              nullptr, 0, a.Azd1 + LATENT, 288, 1, bid, tid, sA, sCo);
    gbar(a.bar, 5, bid);

    // ================= S5: dh2 -> Azd2[:,32:288] ============================
    gemm_stage16<9, EXPERTS>(a.Azd1, a.Wt_w1, a.b1, a.co, 256, 256, 4,
                             nullptr, 0, a.Azd2 + LATENT, 288, 1, bid, tid, sA, sCo);
    gbar(a.bar, 6, bid);

    // ================= S6: out -> d_out (f32) ===============================
    gemm_stage16<9, EXPERTS>(a.Azd2, a.Wt_w2, a.b2, a.co, FRAME, 320, 5,
                             a.out_layer, FRAME, nullptr, 0, 0, bid, tid, sA, sCo);
}

// ---------------------------------------------------------------------------
extern "C" void kernel_launch(void* const* d_in, const int* in_sizes, int n_in,
                              void* d_out, int out_size, void* d_ws, size_t ws_size,
                              hipStream_t stream) {
    Args a;
    a.x       = (const float*)d_in[0];
    a.c       = (const float*)d_in[1];
    a.eps     = (const float*)d_in[2];
    const float* enc_w1  = (const float*)d_in[3];
    a.enc_b1  = (const float*)d_in[4];
    const float* enc_w2  = (const float*)d_in[5];
    a.enc_b2  = (const float*)d_in[6];
    const float* enc_wmu = (const float*)d_in[7];
    a.enc_bmu = (const float*)d_in[8];
    const float* enc_wlv = (const float*)d_in[9];
    a.enc_blv = (const float*)d_in[10];
    const float* g_w0    = (const float*)d_in[11];
    a.g_b0    = (const float*)d_in[12];
    const float* g_w1    = (const float*)d_in[13];
    a.g_b1    = (const float*)d_in[14];
    const float* g_w2    = (const float*)d_in[15];
    a.g_b2    = (const float*)d_in[16];
    const float* w0      = (const float*)d_in[17];
    a.b0      = (const float*)d_in[18];
    const float* w1      = (const float*)d_in[19];
    a.b1      = (const float*)d_in[20];
    const float* w2      = (const float*)d_in[21];
    a.b2      = (const float*)d_in[22];

    a.out_layer = (float*)d_out;
    a.out_mu    = a.out_layer + (size_t)N_BATCH * FRAME;
    a.out_lv    = a.out_mu    + (size_t)N_BATCH * LATENT;

    // ---- workspace layout (16B-aligned) ----
    char* p = (char*)d_ws;
    a.bar     = (unsigned*)p;  p += 2048;              // padded barrier state
    a.co      = (float*)p;     p += (size_t)N_BATCH * EXPERTS * 4;
    a.biasCat = (float*)p;     p += 64 * 4;
    a.Axc  = (bf16*)p;         p += (size_t)N_BATCH * 544 * 2;
    a.Axh1 = (bf16*)p;         p += (size_t)N_BATCH * 544 * 2;
    a.Axh2 = (bf16*)p;         p += (size_t)N_BATCH * 544 * 2;
    a.Azc  = (bf16*)p;         p += (size_t)N_BATCH * 320 * 2;
    a.Azd1 = (bf16*)p;         p += (size_t)N_BATCH * 288 * 2;
    a.Azd2 = (bf16*)p;         p += (size_t)N_BATCH * 288 * 2;
    a.Wt_e1 = (bf16*)p;        p += (size_t)17 * 256 * 32 * 2;
    a.Wt_e2 = (bf16*)p;        p += (size_t)17 * 256 * 32 * 2;
    a.Wt_ml = (bf16*)p;        p += (size_t)17 * 64 * 32 * 2;
    a.Wt_g0 = (bf16*)p;        p += (size_t)10 * 64 * 32 * 2;
    a.Wt_g1 = (bf16*)p;        p += (size_t)2 * 64 * 32 * 2;
    a.Wt_g2 = (bf16*)p;        p += (size_t)2 * 32 * 32 * 2;
    a.Wt_w0 = (bf16*)p;        p += (size_t)EXPERTS * 10 * 256 * 32 * 2;
    a.Wt_w1 = (bf16*)p;        p += (size_t)EXPERTS * 9 * 256 * 32 * 2;
    a.Wt_w2 = (bf16*)p;        p += (size_t)EXPERTS * 9 * 320 * 32 * 2;

    WTab tab;
    int cum = 0, n = 0;
    auto add = [&](const float* src, bf16* dst, int K, int M, int Mtot, int mOff, int E) {
        int Ksteps;
        if (K == 534 || K == 523) Ksteps = 17;
        else if (K == 299) Ksteps = 10;
        else if (K == 288) Ksteps = 9;
        else Ksteps = 2;   // K=64
        const int Mtiles = (M + 31) / 32;
        tab.e[n] = {src, dst, K, M, Mtot, mOff, Ksteps, Mtiles, cum};
        cum += E * Ksteps * Mtiles;
        ++n;
    };
    add(enc_w1,  a.Wt_e1, 534, 256, 256, 0, 1);
    add(enc_w2,  a.Wt_e2, 523, 256, 256, 0, 1);
    add(enc_wmu, a.Wt_ml, 523, 32, 64, 0, 1);
    add(enc_wlv, a.Wt_ml, 523, 32, 64, 32, 1);
    add(g_w0,    a.Wt_g0, 299, 64, 64, 0, 1);
    add(g_w1,    a.Wt_g1, 64, 64, 64, 0, 1);
    add(g_w2,    a.Wt_g2, 64, 6, 32, 0, 1);
    add(w0,      a.Wt_w0, 299, 256, 256, 0, EXPERTS);
    add(w1,      a.Wt_w1, 288, 256, 256, 0, EXPERTS);
    add(w2,      a.Wt_w2, 288, 267, 320, 0, EXPERTS);
    tab.total = cum;

    hipMemsetAsync(a.bar, 0, 2048, stream);   // zero barrier state (poisoned 0xAA)
    fused<<<dim3(NBLK), dim3(256), 0, stream>>>(a, tab);
}

// Round 12
// 370.919 us; speedup vs baseline: 1.4560x; 1.4560x over previous
//
#include <hip/hip_runtime.h>
#include <hip/hip_bf16.h>
#include <math.h>

// Problem constants (PoseMixtureVAE)
#define N_BATCH 4096
#define FRAME   267
#define LATENT  32
#define HIDDEN  256
#define GATE_H  64
#define EXPERTS 6
#define NBLK    512    // persistent grid: lb(256,2) -> 2 blocks/CU guaranteed (R8-verified)

typedef __hip_bfloat16 bf16;
typedef __bf16  bf16x8 __attribute__((ext_vector_type(8)));
typedef float   f32x4  __attribute__((ext_vector_type(4)));

__device__ __forceinline__ float eluf(float v) { return (v > 0.f) ? v : (expf(v) - 1.f); }

// ---------------------------------------------------------------------------
// Two-level grid barrier, monotonic phase. R12 fix vs R11: the spin polls with
// RELAXED agent-scope atomic loads (no per-poll cache invalidate). The fence
// pair (__threadfence before arrival / after exit) provides release/acquire.
// Insurance: one ACQUIRE poll every 4096 spins (guards against stale reads if
// relaxed agent loads ever hit a non-coherent cache).
//   bar[0]        : gen (polled line)
//   bar[32+g*32]  : group counter g=0..7 (64 arrivals each, own line)
//   bar[32+8*32]  : global counter (8 arrivals)
// ---------------------------------------------------------------------------
__device__ __forceinline__ void gbar(unsigned* bar, int phase, int bid) {
    __syncthreads();
    if (threadIdx.x == 0) {
        __threadfence();   // release: drain this block's stores to coherent point
        unsigned* ggen = bar;
        unsigned* grp  = bar + 32 + (bid & 7) * 32;
        unsigned* gcnt = bar + 32 + 8 * 32;
        const unsigned ph = (unsigned)phase;
        unsigned old = __hip_atomic_fetch_add(grp, 1u, __ATOMIC_RELAXED, __HIP_MEMORY_SCOPE_AGENT);
        if (old == 64u * ph - 1u) {
            unsigned o2 = __hip_atomic_fetch_add(gcnt, 1u, __ATOMIC_RELAXED, __HIP_MEMORY_SCOPE_AGENT);
            if (o2 == 8u * ph - 1u)
                __hip_atomic_store(ggen, ph, __ATOMIC_RELAXED, __HIP_MEMORY_SCOPE_AGENT);
        }
        unsigned spins = 0;
        for (;;) {
            unsigned g = ((++spins & 4095u) == 0u)
                ? __hip_atomic_load(ggen, __ATOMIC_ACQUIRE, __HIP_MEMORY_SCOPE_AGENT)
                : __hip_atomic_load(ggen, __ATOMIC_RELAXED, __HIP_MEMORY_SCOPE_AGENT);
            if (g >= ph) break;
            __builtin_amdgcn_s_sleep(2);
        }
        __threadfence();   // acquire: invalidate stale caches before next stage's reads
    }
    __syncthreads();
}

struct WEnt { const float* src; bf16* dst; int K, M, Mtot, mOff, Ksteps, Mtiles, cum; };
struct WTab { WEnt e[10]; int total; };

struct Args {
    const float *x, *c, *eps;
    const float *enc_b1, *enc_b2, *g_b0, *g_b1, *g_b2, *b0, *b1, *b2;
    const float *enc_bmu, *enc_blv;
    float *out_layer, *out_mu, *out_lv;
    unsigned *bar;
    float *co, *biasCat;
    bf16 *Axc, *Axh1, *Axh2, *Azc, *Azd1, *Azd2;
    bf16 *Wt_e1, *Wt_e2, *Wt_ml, *Wt_g0, *Wt_g1, *Wt_g2, *Wt_w0, *Wt_w1, *Wt_w2;
};

// ---------------------------------------------------------------------------
// Persistent GEMM stage (R10's 16-row/RF=1 wave structure):
//   block bid -> row-block bid>>1 (16 rows), col-half bid&1 of TCOL 64-col tiles.
//   A (16 x Kpad) staged once in LDS; B streamed to regs (1KB/wave coalesced
//   from k-block repack [E][KSTEPS][Mtot][32]).
// ---------------------------------------------------------------------------
template<int KSTEPS, int E>
__device__ void gemm_stage16(
    const bf16* __restrict__ A, const bf16* __restrict__ Wt,
    const float* __restrict__ bias, const float* __restrict__ coeff,
    int M, int Mtot, int TCOL,
    float* __restrict__ Cf, int ldc, bf16* __restrict__ Cb, int ldcb, int act,
    int bid, int tid, bf16* sA, float* sCo)
{
    constexpr int Kpad = KSTEPS * 32;
    constexpr int strideA = Kpad + 8;
    const int w = tid >> 6, lane = tid & 63, ml = lane & 15, quad = lane >> 4;
    const int row0 = (bid >> 1) * 16;
    const int ch = bid & 1;
    const int nh = (TCOL + 1) >> 1;
    const int gA = ch * nh;
    const int gB = (gA + nh < TCOL) ? gA + nh : TCOL;

    if (tid < 16 * E) {
        const int e = tid >> 4, r = tid & 15;
        sCo[tid] = coeff ? coeff[(size_t)(row0 + r) * EXPERTS + e] : 1.f;
    }
    {   // stage A: 16 rows x Kpad
        const int r = tid >> 4, kt = (tid & 15) * 8;
        for (int kk = kt; kk < Kpad; kk += 128)
            *(float4*)(sA + r * strideA + kk) =
                *(const float4*)(A + (size_t)(row0 + r) * Kpad + kk);
    }
    __syncthreads();

    for (int g = gA; g < gB; ++g) {
        const int col = g * 64 + 16 * w + ml;
        f32x4 acc = (f32x4){0.f, 0.f, 0.f, 0.f};
        for (int e = 0; e < E; ++e) {
            f32x4 p = (f32x4){0.f, 0.f, 0.f, 0.f};
            const bf16* wp = Wt + ((size_t)e * KSTEPS * Mtot + col) * 32 + quad * 8;
            #pragma unroll
            for (int ks = 0; ks < KSTEPS; ++ks) {
                const bf16x8 b  = *(const bf16x8*)(wp + (size_t)ks * Mtot * 32);
                const bf16x8 av = *(const bf16x8*)(sA + ml * strideA + ks * 32 + quad * 8);
                p = __builtin_amdgcn_mfma_f32_16x16x32_bf16(av, b, p, 0, 0, 0);
            }
            const float bv = (col < M) ? bias[(size_t)e * M + col] : 0.f;
            #pragma unroll
            for (int rg = 0; rg < 4; ++rg)
                acc[rg] += sCo[e * 16 + quad * 4 + rg] * (p[rg] + bv);
        }
        if (col < M) {
            #pragma unroll
            for (int rg = 0; rg < 4; ++rg) {
                const int gr = row0 + quad * 4 + rg;
                float v = acc[rg];
                if (act) v = eluf(v);
                if (Cf) Cf[(size_t)gr * ldc + col] = v;
                if (Cb) Cb[(size_t)gr * ldcb + col] = __float2bfloat16(v);
            }
        }
    }
}

// ---------------------------------------------------------------------------
__global__ __launch_bounds__(256, 2) void fused(Args a, WTab tab) {
    __shared__ bf16  sA[16 * 552];           // 17664B (Kpad<=544, stride 552)
    __shared__ char  r1[8448];               // mid scratch / repack tbuf
    __shared__ float sCo[16 * EXPERTS];      // 384B
    const int tid = threadIdx.x;
    const int bid = blockIdx.x;
    const int w = tid >> 6, lane = tid & 63, ml = lane & 15, quad = lane >> 4;

    // ================= S0: input conversion + weight repack =================
    if (bid == 0 && tid < 64)
        a.biasCat[tid] = (tid < 32) ? a.enc_bmu[tid] : a.enc_blv[tid - 32];
    #pragma unroll 1
    for (int i = 0; i < 8; ++i) {
        const int r = bid * 8 + i;
        for (int col = tid; col < 544; col += 256) {
            const size_t o = (size_t)r * 544 + col;
            float vx = 0.f;
            if (col < FRAME)          vx = a.x[(size_t)r * FRAME + col];
            else if (col < 2 * FRAME) vx = a.c[(size_t)r * FRAME + col - FRAME];
            a.Axc[o] = __float2bfloat16(vx);
            if (col < FRAME) {
                const bf16 v = __float2bfloat16(a.x[(size_t)r * FRAME + col]);
                a.Axh1[o] = v; a.Axh2[o] = v;
            } else if (col >= FRAME + HIDDEN) {
                const bf16 zv = __float2bfloat16(0.f);
                a.Axh1[o] = zv; a.Axh2[o] = zv;
            }
            if (col >= 32 && col < 320) {
                const float vc = (col < 32 + FRAME) ? a.c[(size_t)r * FRAME + col - 32] : 0.f;
                a.Azc[(size_t)r * 320 + col] = __float2bfloat16(vc);
            }
        }
    }
    {   // weight repack units strided over blocks (block-uniform loop count OK)
        float (*tbuf)[33] = (float(*)[33])r1;   // 32x33 f32 = 4224B
        const int tx = tid & 31, ty = tid >> 5;
        #pragma unroll 1
        for (int u = bid; u < tab.total; u += NBLK) {
            int i = 0;
            while (i < 9 && u >= tab.e[i + 1].cum) ++i;
            const WEnt en = tab.e[i];
            const int t = u - en.cum;
            const int perE = en.Ksteps * en.Mtiles;
            const int e = t / perE;
            const int rr = t - e * perE;
            const int mt = rr / en.Ksteps;
            const int ks = rr - mt * en.Ksteps;
            const float* src = en.src + (size_t)e * en.K * en.M;
            __syncthreads();
            #pragma unroll
            for (int i0 = 0; i0 < 32; i0 += 8) {
                const int k = ks * 32 + i0 + ty, m = mt * 32 + tx;
                tbuf[i0 + ty][tx] = (k < en.K && m < en.M) ? src[(size_t)k * en.M + m] : 0.f;
            }
            __syncthreads();
            bf16* dst = en.dst + ((size_t)(e * en.Ksteps + ks) * en.Mtot + en.mOff + mt * 32) * 32;
            #pragma unroll
            for (int i0 = 0; i0 < 32; i0 += 8)
                dst[(size_t)(i0 + ty) * 32 + tx] = __float2bfloat16(tbuf[tx][i0 + ty]);
        }
    }
    gbar(a.bar, 1, bid);

    // ================= S1: h1 = elu([x|c]@W+b) -> Axh1[:,267:523] ===========
    gemm_stage16<17, 1>(a.Axc, a.Wt_e1, a.enc_b1, nullptr, 256, 256, 4,
                        nullptr, 0, a.Axh1 + FRAME, 544, 1, bid, tid, sA, sCo);
    gbar(a.bar, 2, bid);

    // ================= S2: h2 = elu([x|h1]@W+b) -> Axh2[:,267:523] ==========
    gemm_stage16<17, 1>(a.Axh1, a.Wt_e2, a.enc_b2, nullptr, 256, 256, 4,
                        nullptr, 0, a.Axh2 + FRAME, 544, 1, bid, tid, sA, sCo);
    gbar(a.bar, 3, bid);

    // ====== S3: mu|lv GEMM + z + gate chain + softmax (blocks 0..255) =======
    if (bid < 256) {
        const int row0 = bid * 16;
        float* sML = (float*)r1;                       // 16x64 f32 = 4KB
        {   // stage Axh2 rows (Kpad 544, stride 552)
            const int r = tid >> 4, kt = (tid & 15) * 8;
            for (int kk = kt; kk < 544; kk += 128)
                *(float4*)(sA + r * 552 + kk) =
                    *(const float4*)(a.Axh2 + (size_t)(row0 + r) * 544 + kk);
        }
        __syncthreads();
        {   // mu|lv: M=64, wave w -> cols 16w..16w+15
            const int col = 16 * w + ml;
            f32x4 p = (f32x4){0.f, 0.f, 0.f, 0.f};
            const bf16* wp = a.Wt_ml + (size_t)col * 32 + quad * 8;
            #pragma unroll
            for (int ks = 0; ks < 17; ++ks) {
                const bf16x8 b  = *(const bf16x8*)(wp + (size_t)ks * 64 * 32);
                const bf16x8 av = *(const bf16x8*)(sA + ml * 552 + ks * 32 + quad * 8);
                p = __builtin_amdgcn_mfma_f32_16x16x32_bf16(av, b, p, 0, 0, 0);
            }
            const float bv = a.biasCat[col];
            #pragma unroll
            for (int rg = 0; rg < 4; ++rg)
                sML[(quad * 4 + rg) * 64 + col] = p[rg] + bv;
        }
        __syncthreads();
        for (int i = tid; i < 16 * LATENT; i += 256) {
            const int r = i >> 5, l = i & 31;
            const float m  = sML[r * 64 + l];
            const float lv = sML[r * 64 + 32 + l];
            const int gi = (row0 + r) * LATENT + l;
            a.out_mu[gi] = m; a.out_lv[gi] = lv;
            const bf16 zb = __float2bfloat16(m + a.eps[gi] * expf(0.5f * lv));
            a.Azc [(size_t)(row0 + r) * 320 + l] = zb;
            a.Azd1[(size_t)(row0 + r) * 288 + l] = zb;
            a.Azd2[(size_t)(row0 + r) * 288 + l] = zb;
        }
        __syncthreads();
        {   // re-stage gate A = Azc rows [z|c] (Kpad 320, stride 328)
            const int r = tid >> 4, kt = (tid & 15) * 8;
            for (int kk = kt; kk < 320; kk += 128)
                *(float4*)(sA + r * 328 + kk) =
                    *(const float4*)(a.Azc + (size_t)(row0 + r) * 320 + kk);
        }
        bf16*  sG1 = (bf16*)r1;                        // 16x72 bf16 = 2304B
        bf16*  sG2 = (bf16*)(r1 + 2304);
        float* sLg = (float*)(r1 + 4608);              // 16x16 f32 = 1024B
        __syncthreads();
        {   // g1: K=320(10), M=64
            const int col = 16 * w + ml;
            f32x4 p = (f32x4){0.f, 0.f, 0.f, 0.f};
            const bf16* wp = a.Wt_g0 + (size_t)col * 32 + quad * 8;
            #pragma unroll
            for (int ks = 0; ks < 10; ++ks) {
                const bf16x8 b  = *(const bf16x8*)(wp + (size_t)ks * 64 * 32);
                const bf16x8 av = *(const bf16x8*)(sA + ml * 328 + ks * 32 + quad * 8);
                p = __builtin_amdgcn_mfma_f32_16x16x32_bf16(av, b, p, 0, 0, 0);
            }
            const float bv = a.g_b0[col];
            #pragma unroll
            for (int rg = 0; rg < 4; ++rg)
                sG1[(quad * 4 + rg) * 72 + col] = __float2bfloat16(eluf(p[rg] + bv));
        }
        __syncthreads();
        {   // g2: K=64(2), M=64
            const int col = 16 * w + ml;
            f32x4 p = (f32x4){0.f, 0.f, 0.f, 0.f};
            const bf16* wp = a.Wt_g1 + (size_t)col * 32 + quad * 8;
            #pragma unroll
            for (int ks = 0; ks < 2; ++ks) {
                const bf16x8 b  = *(const bf16x8*)(wp + (size_t)ks * 64 * 32);
                const bf16x8 av = *(const bf16x8*)(sG1 + ml * 72 + ks * 32 + quad * 8);
                p = __builtin_amdgcn_mfma_f32_16x16x32_bf16(av, b, p, 0, 0, 0);
            }
            const float bv = a.g_b1[col];
            #pragma unroll
            for (int rg = 0; rg < 4; ++rg)
                sG2[(quad * 4 + rg) * 72 + col] = __float2bfloat16(eluf(p[rg] + bv));
        }
        __syncthreads();
        if (w == 0) {   // logits: K=64(2), M=6 (Mtot 32)
            f32x4 p = (f32x4){0.f, 0.f, 0.f, 0.f};
            const bf16* wp = a.Wt_g2 + (size_t)ml * 32 + quad * 8;
            #pragma unroll
            for (int ks = 0; ks < 2; ++ks) {
                const bf16x8 b  = *(const bf16x8*)(wp + (size_t)ks * 32 * 32);
                const bf16x8 av = *(const bf16x8*)(sG2 + ml * 72 + ks * 32 + quad * 8);
                p = __builtin_amdgcn_mfma_f32_16x16x32_bf16(av, b, p, 0, 0, 0);
            }
            const float bv = (ml < EXPERTS) ? a.g_b2[ml] : 0.f;
            #pragma unroll
            for (int rg = 0; rg < 4; ++rg)
                sLg[(quad * 4 + rg) * 16 + ml] = p[rg] + bv;
        }
        __syncthreads();
        if (tid < 16) {
            float v[EXPERTS];
            float m = -1e30f;
            #pragma unroll
            for (int i = 0; i < EXPERTS; ++i) { v[i] = sLg[tid * 16 + i]; m = fmaxf(m, v[i]); }
            float s = 0.f;
            #pragma unroll
            for (int i = 0; i < EXPERTS; ++i) { v[i] = expf(v[i] - m); s += v[i]; }
            const float inv = 1.f / s;
            #pragma unroll
            for (int i = 0; i < EXPERTS; ++i)
                a.co[(size_t)(row0 + tid) * EXPERTS + i] = v[i] * inv;
        }
    }
    gbar(a.bar, 4, bid);

    // ================= S4: dh1 -> Azd1[:,32:288] ============================
    gemm_stage16<10, EXPERTS>(a.Azc, a.Wt_w0, a.b0, a.co, 256, 256, 4,
                              nullptr, 0, a.Azd1 + LATENT, 288, 1, bid, tid, sA, sCo);
    gbar(a.bar, 5, bid);

    // ================= S5: dh2 -> Azd2[:,32:288] ============================
    gemm_stage16<9, EXPERTS>(a.Azd1, a.Wt_w1, a.b1, a.co, 256, 256, 4,
                             nullptr, 0, a.Azd2 + LATENT, 288, 1, bid, tid, sA, sCo);
    gbar(a.bar, 6, bid);

    // ================= S6: out -> d_out (f32) ===============================
    gemm_stage16<9, EXPERTS>(a.Azd2, a.Wt_w2, a.b2, a.co, FRAME, 320, 5,
                             a.out_layer, FRAME, nullptr, 0, 0, bid, tid, sA, sCo);
}

// ---------------------------------------------------------------------------
extern "C" void kernel_launch(void* const* d_in, const int* in_sizes, int n_in,
                              void* d_out, int out_size, void* d_ws, size_t ws_size,
                              hipStream_t stream) {
    Args a;
    a.x       = (const float*)d_in[0];
    a.c       = (const float*)d_in[1];
    a.eps     = (const float*)d_in[2];
    const float* enc_w1  = (const float*)d_in[3];
    a.enc_b1  = (const float*)d_in[4];
    const float* enc_w2  = (const float*)d_in[5];
    a.enc_b2  = (const float*)d_in[6];
    const float* enc_wmu = (const float*)d_in[7];
    a.enc_bmu = (const float*)d_in[8];
    const float* enc_wlv = (const float*)d_in[9];
    a.enc_blv = (const float*)d_in[10];
    const float* g_w0    = (const float*)d_in[11];
    a.g_b0    = (const float*)d_in[12];
    const float* g_w1    = (const float*)d_in[13];
    a.g_b1    = (const float*)d_in[14];
    const float* g_w2    = (const float*)d_in[15];
    a.g_b2    = (const float*)d_in[16];
    const float* w0      = (const float*)d_in[17];
    a.b0      = (const float*)d_in[18];
    const float* w1      = (const float*)d_in[19];
    a.b1      = (const float*)d_in[20];
    const float* w2      = (const float*)d_in[21];
    a.b2      = (const float*)d_in[22];

    a.out_layer = (float*)d_out;
    a.out_mu    = a.out_layer + (size_t)N_BATCH * FRAME;
    a.out_lv    = a.out_mu    + (size_t)N_BATCH * LATENT;

    // ---- workspace layout (16B-aligned) ----
    char* p = (char*)d_ws;
    a.bar     = (unsigned*)p;  p += 2048;              // padded barrier state
    a.co      = (float*)p;     p += (size_t)N_BATCH * EXPERTS * 4;
    a.biasCat = (float*)p;     p += 64 * 4;
    a.Axc  = (bf16*)p;         p += (size_t)N_BATCH * 544 * 2;
    a.Axh1 = (bf16*)p;         p += (size_t)N_BATCH * 544 * 2;
    a.Axh2 = (bf16*)p;         p += (size_t)N_BATCH * 544 * 2;
    a.Azc  = (bf16*)p;         p += (size_t)N_BATCH * 320 * 2;
    a.Azd1 = (bf16*)p;         p += (size_t)N_BATCH * 288 * 2;
    a.Azd2 = (bf16*)p;         p += (size_t)N_BATCH * 288 * 2;
    a.Wt_e1 = (bf16*)p;        p += (size_t)17 * 256 * 32 * 2;
    a.Wt_e2 = (bf16*)p;        p += (size_t)17 * 256 * 32 * 2;
    a.Wt_ml = (bf16*)p;        p += (size_t)17 * 64 * 32 * 2;
    a.Wt_g0 = (bf16*)p;        p += (size_t)10 * 64 * 32 * 2;
    a.Wt_g1 = (bf16*)p;        p += (size_t)2 * 64 * 32 * 2;
    a.Wt_g2 = (bf16*)p;        p += (size_t)2 * 32 * 32 * 2;
    a.Wt_w0 = (bf16*)p;        p += (size_t)EXPERTS * 10 * 256 * 32 * 2;
    a.Wt_w1 = (bf16*)p;        p += (size_t)EXPERTS * 9 * 256 * 32 * 2;
    a.Wt_w2 = (bf16*)p;        p += (size_t)EXPERTS * 9 * 320 * 32 * 2;

    WTab tab;
    int cum = 0, n = 0;
    auto add = [&](const float* src, bf16* dst, int K, int M, int Mtot, int mOff, int E) {
        int Ksteps;
        if (K == 534 || K == 523) Ksteps = 17;
        else if (K == 299) Ksteps = 10;
        else if (K == 288) Ksteps = 9;
        else Ksteps = 2;   // K=64
        const int Mtiles = (M + 31) / 32;
        tab.e[n] = {src, dst, K, M, Mtot, mOff, Ksteps, Mtiles, cum};
        cum += E * Ksteps * Mtiles;
        ++n;
    };
    add(enc_w1,  a.Wt_e1, 534, 256, 256, 0, 1);
    add(enc_w2,  a.Wt_e2, 523, 256, 256, 0, 1);
    add(enc_wmu, a.Wt_ml, 523, 32, 64, 0, 1);
    add(enc_wlv, a.Wt_ml, 523, 32, 64, 32, 1);
    add(g_w0,    a.Wt_g0, 299, 64, 64, 0, 1);
    add(g_w1,    a.Wt_g1, 64, 64, 64, 0, 1);
    add(g_w2,    a.Wt_g2, 64, 6, 32, 0, 1);
    add(w0,      a.Wt_w0, 299, 256, 256, 0, EXPERTS);
    add(w1,      a.Wt_w1, 288, 256, 256, 0, EXPERTS);
    add(w2,      a.Wt_w2, 288, 267, 320, 0, EXPERTS);
    tab.total = cum;

    hipMemsetAsync(a.bar, 0, 2048, stream);   // zero barrier state (poisoned 0xAA)
    fused<<<dim3(NBLK), dim3(256), 0, stream>>>(a, tab);
}